// Round 5
// baseline (242.269 us; speedup 1.0000x reference)
//
#include <hip/hip_runtime.h>

#define NB 16
#define NE 4
#define NC 4
#define NPIX (512 * 1024)

constexpr int THREADS         = 512;               // 8 waves
constexpr int TILE_PX         = 2048;              // pixels per tile
constexpr int TILE_B          = TILE_PX * 4;       // 8 KB per stream per tile
constexpr int NSTREAM         = 6;                 // p0..p3, mask, inst
constexpr int BUF_B           = NSTREAM * TILE_B;  // 48 KB
constexpr int TILES_PER_BLOCK = 16;
constexpr int BPB             = (NPIX / TILE_PX) / TILES_PER_BLOCK;  // 16 blocks/batch
#define WS_STRIDE 36
// ws[(by*BPB + bx)*36 + t]; t: [0..15]=sum[c*4+e], [16..31]=sumsq, [32..35]=count[c]

typedef float f32x4 __attribute__((ext_vector_type(4)));
typedef int   i32x4 __attribute__((ext_vector_type(4)));

// Stage one 2048-px tile: 48 wave-loads of 1KB; wave w issues 6, each a
// contiguous run of ONE stream (idx = w*6+i; s = idx/8, run = idx%8).
// global_load_lds: LDS dest = uniform base + lane*16 (linear), global src per-lane.
__device__ __forceinline__ void stage_tile(
    const char* __restrict__ predB, const char* __restrict__ maskB,
    const char* __restrict__ instB, char* smem, int dbuf, int wave, int lane,
    size_t px0)
{
    #pragma unroll
    for (int i = 0; i < 6; ++i) {
        const int idx = wave * 6 + i;       // 0..47, wave-uniform
        const int s   = idx >> 3;           // stream 0..5
        const int run = idx & 7;            // 1KB run within the 8KB stream tile
        const char* g;
        if (s < 4)       g = predB + (size_t)s * (NPIX * 4) + px0 * 4 + run * 1024;
        else if (s == 4) g = maskB + px0 * 4 + run * 1024;
        else             g = instB + px0 * 4 + run * 1024;
        g += lane * 16;
        char* l = smem + dbuf * BUF_B + s * TILE_B + run * 1024;
        __builtin_amdgcn_global_load_lds(
            (const __attribute__((address_space(1))) void*)g,
            (__attribute__((address_space(3))) void*)l, 16, 0, 0);
    }
}

__global__ __launch_bounds__(THREADS) void accum_kernel(
    const float* __restrict__ pred,
    const float* __restrict__ mask,
    const int*   __restrict__ inst,
    float* __restrict__ ws)
{
    __shared__ char smem[2 * BUF_B];   // 96 KB -> 1 block/CU

    const int tid  = threadIdx.x;
    const int wave = tid >> 6;
    const int lane = tid & 63;
    const int by   = blockIdx.y;       // batch
    const int bx   = blockIdx.x;       // block within batch

    const char* predB = (const char*)pred + (size_t)by * 4 * NPIX * 4;
    const char* maskB = (const char*)mask + (size_t)by * NPIX * 4;
    const char* instB = (const char*)inst + (size_t)by * NPIX * 4;
    const size_t pxBase = (size_t)bx * (TILES_PER_BLOCK * TILE_PX);

    float s_[NC][NE] = {};
    float q_[NC][NE] = {};
    float n_[NC]     = {};

    stage_tile(predB, maskB, instB, smem, 0, wave, lane, pxBase);
    __syncthreads();   // drains vmcnt -> buf0 ready

    #pragma unroll 1
    for (int t = 0; t < TILES_PER_BLOCK; ++t) {
        const int cur = t & 1, nxt = cur ^ 1;
        if (t + 1 < TILES_PER_BLOCK)
            stage_tile(predB, maskB, instB, smem, nxt, wave, lane,
                       pxBase + (size_t)(t + 1) * TILE_PX);   // in flight under compute

        // compute: 4 px/thread from buf[cur]
        const char* base = smem + cur * BUF_B;
        const int   off  = tid * 16;
        f32x4 p4[NE];
        p4[0] = *(const f32x4*)(base + 0 * TILE_B + off);
        p4[1] = *(const f32x4*)(base + 1 * TILE_B + off);
        p4[2] = *(const f32x4*)(base + 2 * TILE_B + off);
        p4[3] = *(const f32x4*)(base + 3 * TILE_B + off);
        const f32x4 m4 = *(const f32x4*)(base + 4 * TILE_B + off);
        const i32x4 i4 = *(const i32x4*)(base + 5 * TILE_B + off);

        #pragma unroll
        for (int j = 0; j < 4; ++j) {
            const float mm  = m4[j];
            const int   lab = i4[j];
            float v[NE], sq[NE];
            #pragma unroll
            for (int e = 0; e < NE; ++e) {
                const float x = mm * p4[e][j];
                v[e]  = x;
                sq[e] = x * x;
            }
            #pragma unroll
            for (int c = 0; c < NC; ++c) {
                const float ind = (lab == c + 1) ? 1.0f : 0.0f;
                n_[c] += ind;
                #pragma unroll
                for (int e = 0; e < NE; ++e) {
                    s_[c][e] = fmaf(ind, v[e],  s_[c][e]);
                    q_[c][e] = fmaf(ind, sq[e], q_[c][e]);
                }
            }
        }
        __syncthreads();   // next tile's loads landed; buf[cur] free to overwrite
    }

    // cheap tail: quad butterfly then LDS combine (reuse smem), no atomics
    #pragma unroll
    for (int c = 0; c < NC; ++c) {
        #pragma unroll
        for (int e = 0; e < NE; ++e) {
            s_[c][e] += __shfl_xor(s_[c][e], 1); s_[c][e] += __shfl_xor(s_[c][e], 2);
            q_[c][e] += __shfl_xor(q_[c][e], 1); q_[c][e] += __shfl_xor(q_[c][e], 2);
        }
        n_[c] += __shfl_xor(n_[c], 1); n_[c] += __shfl_xor(n_[c], 2);
    }

    float* redf = (float*)smem;        // 128 rows x 36 floats = 18 KB
    if ((lane & 3) == 0) {
        float* dst = redf + (wave * 16 + (lane >> 2)) * WS_STRIDE;
        #pragma unroll
        for (int c = 0; c < NC; ++c) {
            #pragma unroll
            for (int e = 0; e < NE; ++e) {
                dst[c * 4 + e]      = s_[c][e];
                dst[16 + c * 4 + e] = q_[c][e];
            }
            dst[32 + c] = n_[c];
        }
    }
    __syncthreads();

    if (tid < WS_STRIDE) {
        float tot = 0.0f;
        #pragma unroll
        for (int r = 0; r < 128; ++r) tot += redf[r * WS_STRIDE + tid];
        ws[((size_t)(by * BPB + bx)) * WS_STRIDE + tid] = tot;
    }
}

constexpr int FT = 640;
__global__ __launch_bounds__(FT) void finalize_kernel(
    const float* __restrict__ ws, float* __restrict__ out)
{
    __shared__ float fin[NB * WS_STRIDE];   // 576
    const int t = threadIdx.x;
    if (t < NB * WS_STRIDE) {
        const int b = t / WS_STRIDE, v = t % WS_STRIDE;
        float tot = 0.0f;
        #pragma unroll
        for (int blk = 0; blk < BPB; ++blk)
            tot += ws[((size_t)(b * BPB + blk)) * WS_STRIDE + v];
        fin[t] = tot;
    }
    __syncthreads();

    if (t < 64) {
        const int lane = t;
        const int b = lane >> 2;
        const int c = lane & 3;
        const float* wb = fin + b * WS_STRIDE;

        const float cnt = wb[32 + c];
        float mu[NE];
        float ssd = 0.0f;
        #pragma unroll
        for (int e = 0; e < NE; ++e) {
            const float sm = wb[c * 4 + e];
            const float qq = wb[16 + c * 4 + e];
            const float m  = sm / cnt;
            mu[e] = m;
            ssd += qq - cnt * m * m;
        }
        ssd = fmaxf(ssd, 0.0f);
        const float nrm = sqrtf(ssd);
        const float dv  = nrm - 0.5f;
        float var = (nrm > 0.5f) ? dv * dv : 0.0f;

        float dsum = 0.0f;
        const int qbase = lane & ~3;
        #pragma unroll
        for (int j = 0; j < NC; ++j) {
            float d2 = 0.0f;
            #pragma unroll
            for (int e = 0; e < NE; ++e) {
                const float mj = __shfl(mu[e], qbase + j);
                const float df = mu[e] - mj;
                d2 = fmaf(df, df, d2);
            }
            if (j != c) {
                const float dist = sqrtf(d2);
                const float r = fmaxf(3.0f - dist, 0.0f);
                dsum += r * r;
            }
        }

        #pragma unroll
        for (int off = 32; off; off >>= 1) {
            var  += __shfl_xor(var,  off);
            dsum += __shfl_xor(dsum, off);
        }
        if (lane == 0)
            out[0] = var / (float)(NB * NC) + dsum / (float)NB;
    }
}

extern "C" void kernel_launch(void* const* d_in, const int* in_sizes, int n_in,
                              void* d_out, int out_size, void* d_ws, size_t ws_size,
                              hipStream_t stream) {
    const float* pred = (const float*)d_in[0];
    const float* mask = (const float*)d_in[1];
    const int*   inst = (const int*)d_in[2];
    float* out = (float*)d_out;
    float* ws  = (float*)d_ws;

    dim3 grid(BPB, NB);   // 16 x 16 = 256 blocks, 1/CU
    accum_kernel<<<grid, THREADS, 0, stream>>>(pred, mask, inst, ws);
    finalize_kernel<<<1, FT, 0, stream>>>(ws, out);
}

// Round 7
// 240.207 us; speedup vs baseline: 1.0086x; 1.0086x over previous
//
#include <hip/hip_runtime.h>

#define NB 16
#define NE 4
#define NC 4
#define NPIX (512 * 1024)

typedef float f32x4 __attribute__((ext_vector_type(4)));
typedef int   i32x4 __attribute__((ext_vector_type(4)));
typedef unsigned char u8;

// ws layout (bytes):
//   [0, KEYS_B)            keys: 1 B/px, key = lab | (mask!=0 ? 8 : 0)   (8 MB)
//   [KEYS_B, +4096)        pass1 count partials: [(b*16+chunk)][c] floats (1024 f)
//   [KEYS_B+4096, +8192)   pass2 s/q partials: [(plane*4+chunk)][8] floats (2048 f)
constexpr size_t KEYS_B = (size_t)NB * NPIX;

constexpr int P1_THREADS = 512;
constexpr int P1_CHUNKS  = 16;                                   // per batch
constexpr int P1_PXB     = NPIX / P1_CHUNKS;                     // 32768 px/block
constexpr int P1_ITERS   = P1_PXB / (P1_THREADS * 4);            // 16

constexpr int P2_THREADS = 512;
constexpr int P2_CHUNKS  = 4;                                    // per plane
constexpr int P2_PXB     = NPIX / P2_CHUNKS;                     // 131072 px/block
constexpr int P2_ITERS   = P2_PXB / (P2_THREADS * 4);            // 64

__global__ __launch_bounds__(P1_THREADS) void key_kernel(
    const float* __restrict__ mask, const int* __restrict__ inst,
    u8* __restrict__ keys, float* __restrict__ npart)
{
    const int b = blockIdx.y, chunk = blockIdx.x, tid = threadIdx.x;
    const size_t px0 = (size_t)chunk * P1_PXB;
    const f32x4* pm = (const f32x4*)(mask + (size_t)b * NPIX + px0);
    const i32x4* pi = (const i32x4*)(inst + (size_t)b * NPIX + px0);
    unsigned int* ko = (unsigned int*)(keys + (size_t)b * NPIX + px0);

    float n[NC] = {};

    #pragma unroll 4
    for (int it = 0; it < P1_ITERS; ++it) {
        const int u = it * P1_THREADS + tid;
        const f32x4 m4 = pm[u];
        const i32x4 i4 = pi[u];
        unsigned int packed = 0;
        #pragma unroll
        for (int j = 0; j < 4; ++j) {
            const int   lab = i4[j];
            const float mm  = m4[j];
            const unsigned int k = (unsigned int)lab | (mm != 0.0f ? 8u : 0u);
            packed |= k << (8 * j);
            #pragma unroll
            for (int c = 0; c < NC; ++c)
                n[c] += (lab == c + 1) ? 1.0f : 0.0f;
        }
        ko[u] = packed;
    }

    const int lane = tid & 63, wave = tid >> 6;
    #pragma unroll
    for (int c = 0; c < NC; ++c)
        #pragma unroll
        for (int off = 32; off; off >>= 1)
            n[c] += __shfl_xor(n[c], off);

    __shared__ float red[8][NC];
    if (lane == 0) {
        #pragma unroll
        for (int c = 0; c < NC; ++c) red[wave][c] = n[c];
    }
    __syncthreads();
    if (tid < NC) {
        float t = 0.0f;
        #pragma unroll
        for (int w = 0; w < 8; ++w) t += red[w][tid];
        npart[(b * P1_CHUNKS + chunk) * NC + tid] = t;
    }
}

__global__ __launch_bounds__(P2_THREADS) void moment_kernel(
    const float* __restrict__ pred, const u8* __restrict__ keys,
    float* __restrict__ sqpart)
{
    const int chunk = blockIdx.x;     // 0..3
    const int plane = blockIdx.y;     // 0..63 : b = plane>>2, e = plane&3
    const int b     = plane >> 2;
    const int tid   = threadIdx.x;
    const size_t px0 = (size_t)chunk * P2_PXB;
    const f32x4* pp = (const f32x4*)(pred + (size_t)plane * NPIX + px0);
    const unsigned int* pk = (const unsigned int*)(keys + (size_t)b * NPIX + px0);

    float s[NC] = {}, q[NC] = {};

    #pragma unroll 4
    for (int it = 0; it < P2_ITERS; ++it) {
        const int u = it * P2_THREADS + tid;
        const f32x4 p4 = pp[u];                 // the single fat stream
        const unsigned int k4 = pk[u];          // 1/16-rate side stream
        #pragma unroll
        for (int j = 0; j < 4; ++j) {
            const float x  = p4[j];
            const float x2 = x * x;
            const int   k  = (int)((k4 >> (8 * j)) & 0xffu);
            #pragma unroll
            for (int c = 0; c < NC; ++c) {
                const float ind = (k == 9 + c) ? 1.0f : 0.0f;  // mask set && lab==c+1
                s[c] = fmaf(ind, x,  s[c]);
                q[c] = fmaf(ind, x2, q[c]);
            }
        }
    }

    const int lane = tid & 63, wave = tid >> 6;
    #pragma unroll
    for (int c = 0; c < NC; ++c) {
        #pragma unroll
        for (int off = 32; off; off >>= 1) {
            s[c] += __shfl_xor(s[c], off);
            q[c] += __shfl_xor(q[c], off);
        }
    }

    __shared__ float red[8][8];
    if (lane == 0) {
        #pragma unroll
        for (int c = 0; c < NC; ++c) { red[wave][c] = s[c]; red[wave][4 + c] = q[c]; }
    }
    __syncthreads();
    if (tid < 8) {
        float t = 0.0f;
        #pragma unroll
        for (int w = 0; w < 8; ++w) t += red[w][tid];
        sqpart[((plane << 2) | chunk) * 8 + tid] = t;
    }
}

__global__ __launch_bounds__(64) void finalize_kernel(
    const float* __restrict__ npart, const float* __restrict__ sqpart,
    float* __restrict__ out)
{
    const int lane = threadIdx.x;   // (b, c)
    const int b = lane >> 2;
    const int c = lane & 3;

    float cnt = 0.0f;
    #pragma unroll
    for (int ch = 0; ch < P1_CHUNKS; ++ch)
        cnt += npart[(b * P1_CHUNKS + ch) * NC + c];

    float mu[NE];
    float ssd = 0.0f;
    #pragma unroll
    for (int e = 0; e < NE; ++e) {
        const int plane = b * NE + e;
        float se = 0.0f, qe = 0.0f;
        #pragma unroll
        for (int ch = 0; ch < P2_CHUNKS; ++ch) {
            se += sqpart[((plane << 2) | ch) * 8 + c];
            qe += sqpart[((plane << 2) | ch) * 8 + 4 + c];
        }
        const float m = se / cnt;
        mu[e] = m;
        ssd += qe - cnt * m * m;
    }
    ssd = fmaxf(ssd, 0.0f);
    const float nrm = sqrtf(ssd);
    const float dv  = nrm - 0.5f;
    float var = (nrm > 0.5f) ? dv * dv : 0.0f;

    float dsum = 0.0f;
    const int qbase = lane & ~3;
    #pragma unroll
    for (int j = 0; j < NC; ++j) {
        float d2 = 0.0f;
        #pragma unroll
        for (int e = 0; e < NE; ++e) {
            const float mj = __shfl(mu[e], qbase + j);
            const float df = mu[e] - mj;
            d2 = fmaf(df, df, d2);
        }
        if (j != c) {
            const float dist = sqrtf(d2);
            const float r = fmaxf(3.0f - dist, 0.0f);
            dsum += r * r;
        }
    }

    #pragma unroll
    for (int off = 32; off; off >>= 1) {
        var  += __shfl_xor(var,  off);
        dsum += __shfl_xor(dsum, off);
    }
    if (lane == 0)
        out[0] = var / (float)(NB * NC) + dsum / (float)NB;
}

extern "C" void kernel_launch(void* const* d_in, const int* in_sizes, int n_in,
                              void* d_out, int out_size, void* d_ws, size_t ws_size,
                              hipStream_t stream) {
    const float* pred = (const float*)d_in[0];
    const float* mask = (const float*)d_in[1];
    const int*   inst = (const int*)d_in[2];
    float* out = (float*)d_out;

    u8*    keys   = (u8*)d_ws;
    float* npart  = (float*)((char*)d_ws + KEYS_B);
    float* sqpart = npart + 1024;

    dim3 g1(P1_CHUNKS, NB);     // 256 blocks
    key_kernel<<<g1, P1_THREADS, 0, stream>>>(mask, inst, keys, npart);

    dim3 g2(P2_CHUNKS, NB * NE);  // 4 x 64 = 256 blocks
    moment_kernel<<<g2, P2_THREADS, 0, stream>>>(pred, keys, sqpart);

    finalize_kernel<<<1, 64, 0, stream>>>(npart, sqpart, out);
}

// Round 8
// 225.355 us; speedup vs baseline: 1.0751x; 1.0659x over previous
//
#include <hip/hip_runtime.h>

#define NB 16
#define NE 4
#define NC 4
#define NPIX (512 * 1024)

constexpr int THREADS = 256;
constexpr int BPB     = 128;                      // blocks per batch -> 2048 blocks
constexpr int UNITS   = NPIX / 4;                 // 131072 float4 units per batch
constexpr int ITERS   = UNITS / (BPB * THREADS);  // 4
#define WS_STRIDE 36
// ws[(b*BPB + bx)*36 + t]; t: [0..15]=sum[c*4+e], [16..31]=sumsq, [32..35]=count[c]

typedef float f32x4 __attribute__((ext_vector_type(4)));
typedef int   i32x4 __attribute__((ext_vector_type(4)));

__global__ __launch_bounds__(THREADS) void accum_kernel(
    const float* __restrict__ pred,
    const float* __restrict__ mask,
    const int*   __restrict__ inst,
    float* __restrict__ ws)
{
    const int b   = blockIdx.y;
    const int bx  = blockIdx.x;
    const int tid = threadIdx.x;

    float s[NC][NE] = {};
    float q[NC][NE] = {};
    float n[NC]     = {};

    const f32x4* pm  = reinterpret_cast<const f32x4*>(mask + (size_t)b * NPIX);
    const i32x4* pi  = reinterpret_cast<const i32x4*>(inst + (size_t)b * NPIX);
    const f32x4* pp0 = reinterpret_cast<const f32x4*>(pred + ((size_t)b * NE + 0) * NPIX);
    const f32x4* pp1 = reinterpret_cast<const f32x4*>(pred + ((size_t)b * NE + 1) * NPIX);
    const f32x4* pp2 = reinterpret_cast<const f32x4*>(pred + ((size_t)b * NE + 2) * NPIX);
    const f32x4* pp3 = reinterpret_cast<const f32x4*>(pred + ((size_t)b * NE + 3) * NPIX);

    #pragma unroll
    for (int k = 0; k < ITERS; ++k) {
        // lockstep sweep (R4's best structure) + NONTEMPORAL loads (the one
        // untested variable: bypass cache-allocate on the read path)
        const int u = k * (BPB * THREADS) + bx * THREADS + tid;

        const f32x4 m4 = __builtin_nontemporal_load(pm + u);
        const i32x4 i4 = __builtin_nontemporal_load(pi + u);
        f32x4 p4[NE];
        p4[0] = __builtin_nontemporal_load(pp0 + u);
        p4[1] = __builtin_nontemporal_load(pp1 + u);
        p4[2] = __builtin_nontemporal_load(pp2 + u);
        p4[3] = __builtin_nontemporal_load(pp3 + u);

        #pragma unroll
        for (int j = 0; j < 4; ++j) {
            const float mm  = m4[j];
            const int   lab = i4[j];
            float v[NE], sq[NE];
            #pragma unroll
            for (int e = 0; e < NE; ++e) {
                const float x = mm * p4[e][j];
                v[e]  = x;
                sq[e] = x * x;
            }
            #pragma unroll
            for (int c = 0; c < NC; ++c) {
                const float ind = (lab == c + 1) ? 1.0f : 0.0f;
                n[c] += ind;
                #pragma unroll
                for (int e = 0; e < NE; ++e) {
                    s[c][e] = fmaf(ind, v[e],  s[c][e]);
                    q[c][e] = fmaf(ind, sq[e], q[c][e]);
                }
            }
        }
    }

    // cheap tail: 2-step quad butterfly, then one LDS pass, per-block slot (no atomics)
    #pragma unroll
    for (int c = 0; c < NC; ++c) {
        #pragma unroll
        for (int e = 0; e < NE; ++e) {
            s[c][e] += __shfl_xor(s[c][e], 1); s[c][e] += __shfl_xor(s[c][e], 2);
            q[c][e] += __shfl_xor(q[c][e], 1); q[c][e] += __shfl_xor(q[c][e], 2);
        }
        n[c] += __shfl_xor(n[c], 1); n[c] += __shfl_xor(n[c], 2);
    }

    __shared__ float red[64][WS_STRIDE];
    const int lane = tid & 63, wave = tid >> 6;
    if ((lane & 3) == 0) {
        float* dst = red[wave * 16 + (lane >> 2)];
        #pragma unroll
        for (int c = 0; c < NC; ++c) {
            #pragma unroll
            for (int e = 0; e < NE; ++e) {
                dst[c * 4 + e]      = s[c][e];
                dst[16 + c * 4 + e] = q[c][e];
            }
            dst[32 + c] = n[c];
        }
    }
    __syncthreads();

    if (tid < WS_STRIDE) {
        float tot = 0.0f;
        #pragma unroll
        for (int p2 = 0; p2 < 64; ++p2) tot += red[p2][tid];
        ws[((size_t)(b * BPB + bx)) * WS_STRIDE + tid] = tot;
    }
}

constexpr int FT = 640;
__global__ __launch_bounds__(FT) void finalize_kernel(
    const float* __restrict__ ws, float* __restrict__ out)
{
    __shared__ float fin[NB * WS_STRIDE];   // 576
    const int t = threadIdx.x;
    if (t < NB * WS_STRIDE) {
        const int b = t / WS_STRIDE, v = t % WS_STRIDE;
        float tot = 0.0f;
        #pragma unroll 8
        for (int blk = 0; blk < BPB; ++blk)
            tot += ws[((size_t)(b * BPB + blk)) * WS_STRIDE + v];
        fin[t] = tot;
    }
    __syncthreads();

    if (t < 64) {
        const int lane = t;
        const int b = lane >> 2;
        const int c = lane & 3;
        const float* wb = fin + b * WS_STRIDE;

        const float cnt = wb[32 + c];
        float mu[NE];
        float ssd = 0.0f;
        #pragma unroll
        for (int e = 0; e < NE; ++e) {
            const float sm = wb[c * 4 + e];
            const float qq = wb[16 + c * 4 + e];
            const float m  = sm / cnt;
            mu[e] = m;
            ssd += qq - cnt * m * m;
        }
        ssd = fmaxf(ssd, 0.0f);
        const float nrm = sqrtf(ssd);
        const float dv  = nrm - 0.5f;
        float var = (nrm > 0.5f) ? dv * dv : 0.0f;

        float dsum = 0.0f;
        const int qbase = lane & ~3;
        #pragma unroll
        for (int j = 0; j < NC; ++j) {
            float d2 = 0.0f;
            #pragma unroll
            for (int e = 0; e < NE; ++e) {
                const float mj = __shfl(mu[e], qbase + j);
                const float df = mu[e] - mj;
                d2 = fmaf(df, df, d2);
            }
            if (j != c) {
                const float dist = sqrtf(d2);
                const float r = fmaxf(3.0f - dist, 0.0f);
                dsum += r * r;
            }
        }

        #pragma unroll
        for (int off = 32; off; off >>= 1) {
            var  += __shfl_xor(var,  off);
            dsum += __shfl_xor(dsum, off);
        }
        if (lane == 0)
            out[0] = var / (float)(NB * NC) + dsum / (float)NB;
    }
}

extern "C" void kernel_launch(void* const* d_in, const int* in_sizes, int n_in,
                              void* d_out, int out_size, void* d_ws, size_t ws_size,
                              hipStream_t stream) {
    const float* pred = (const float*)d_in[0];
    const float* mask = (const float*)d_in[1];
    const int*   inst = (const int*)d_in[2];
    float* out = (float*)d_out;
    float* ws  = (float*)d_ws;

    dim3 grid(BPB, NB);
    accum_kernel<<<grid, THREADS, 0, stream>>>(pred, mask, inst, ws);
    finalize_kernel<<<1, FT, 0, stream>>>(ws, out);
}